// Round 8
// baseline (147.533 us; speedup 1.0000x reference)
//
#include <hip/hip_runtime.h>
#include <math.h>

#define SEQ  2048
#define ROWS 4096
#define D0   512
#define D1   64

typedef short bf8 __attribute__((ext_vector_type(8)));   // 8 bf16 = 4 VGPRs
typedef float f4  __attribute__((ext_vector_type(4)));   // MFMA acc

// fp32 -> bf16 (RNE) and hi/lo split
__device__ __forceinline__ unsigned short f2bf(float f) {
    unsigned u = __float_as_uint(f);
    return (unsigned short)((u + 0x7fffu + ((u >> 16) & 1u)) >> 16);
}
__device__ __forceinline__ float bf2f(unsigned short u) {
    return __uint_as_float((unsigned)u << 16);
}
__device__ __forceinline__ void hilo(float f, unsigned short& h, unsigned short& l) {
    h = f2bf(f);
    float fh = bf2f(h);
    l = f2bf(f - fh);
}
__device__ __forceinline__ void cv4h(unsigned short* dh, int idx, float4 v) {
    ushort4 hv;
    hv.x = f2bf(v.x); hv.y = f2bf(v.y); hv.z = f2bf(v.z); hv.w = f2bf(v.w);
    *(ushort4*)(dh + idx) = hv;
}

// async global->LDS 16B (dest = wave-uniform base + lane*16)
__device__ __forceinline__ void async16(const void* g, void* l) {
    __builtin_amdgcn_global_load_lds(
        (const __attribute__((address_space(1))) unsigned int*)g,
        (__attribute__((address_space(3))) unsigned int*)l, 16, 0, 0);
}

// ---------------------------------------------------------------------------
// convk: x -> xh+xl (hi/lo); weights -> bf16 hi; A3 transpose;
// G2y[jm,j] = sum_c A1[c,jm]*M2[j,c]; G2r[jm,i] = sum_c A1[c,jm]*R2[i,c];
// SU1[jm] = sum_c g1[c]*B1[jm,c]; SBB1[jm] = sum_c b1[c]*B1[jm,c].
// ---------------------------------------------------------------------------
__global__ __launch_bounds__(256) void convk(
        const float* __restrict__ x,  const float* __restrict__ W1,
        const float* __restrict__ M2, const float* __restrict__ R2,
        const float* __restrict__ W3, const float* __restrict__ R3,
        const float* __restrict__ A1, const float* __restrict__ A3,
        const float* __restrict__ g1, const float* __restrict__ b1,
        const float* __restrict__ B1,
        unsigned short* __restrict__ xh, unsigned short* __restrict__ xl,
        unsigned short* __restrict__ W1h,    // head of 640-row Wbig region
        unsigned short* __restrict__ C2h,    // rows 512..639 of Wbig (M2;R2)
        unsigned short* __restrict__ C3h,
        float* __restrict__ A3T,
        float* __restrict__ G2y, float* __restrict__ G2r,
        float* __restrict__ SU1, float* __restrict__ SBB1) {
    __shared__ float sh[4][64];
    int c = blockIdx.x, tid = threadIdx.x;
    if (c < 1024) {
        int base = c * 2048 + tid * 4;
        float4 v0 = *(const float4*)(x + base);
        float4 v1 = *(const float4*)(x + base + 1024);
        ushort4 h, l;
        hilo(v0.x, h.x, l.x); hilo(v0.y, h.y, l.y);
        hilo(v0.z, h.z, l.z); hilo(v0.w, h.w, l.w);
        *(ushort4*)(xh + base) = h; *(ushort4*)(xl + base) = l;
        hilo(v1.x, h.x, l.x); hilo(v1.y, h.y, l.y);
        hilo(v1.z, h.z, l.z); hilo(v1.w, h.w, l.w);
        *(ushort4*)(xh + base + 1024) = h; *(ushort4*)(xl + base + 1024) = l;
    } else if (c < 1216) {
        const float* src; unsigned short* dh; int off;
        if      (c < 1152) { src = W1; dh = W1h;         off = c - 1024; }
        else if (c < 1168) { src = M2; dh = C2h;         off = c - 1152; }
        else if (c < 1184) { src = R2; dh = C2h + 32768; off = c - 1168; }
        else if (c < 1200) { src = W3; dh = C3h;         off = c - 1184; }
        else               { src = R3; dh = C3h + 32768; off = c - 1200; }
        int base = off * 2048 + tid * 4;
        cv4h(dh, base,        *(const float4*)(src + base));
        cv4h(dh, base + 1024, *(const float4*)(src + base + 1024));
    } else if (c < 1344) {
        int gid = (c - 1216) * 256 + tid;     // 0..32767
        int i = gid >> 6, j = gid & 63;       // A3 (512 x 64)
        A3T[j * 512 + i] = A3[gid];
    } else if (c < 1472) {
        // G blocks: 1344..1407 -> G2y rows j; 1408..1471 -> G2r rows i
        int jrow = (c - 1344) & 63;
        const float* wv = (c < 1408) ? (M2 + jrow * 512) : (R2 + jrow * 512);
        float* G = (c < 1408) ? G2y : G2r;
        int jm = tid & 63, q = tid >> 6;
        const float* ap = A1 + (q * 128) * 64 + jm;
        const float* wp = wv + q * 128;
        float acc = 0.f;
        for (int cc = 0; cc < 128; ++cc)
            acc = fmaf(ap[cc * 64], wp[cc], acc);
        sh[q][jm] = acc;
        __syncthreads();
        if (tid < 64)
            G[tid * 64 + jrow] = (sh[0][tid] + sh[1][tid]) + (sh[2][tid] + sh[3][tid]);
    } else {
        // c == 1472 -> SU1; c == 1473 -> SBB1  (64 jm x 4 k-chunks)
        const float* vec = (c == 1472) ? g1 : b1;
        float* dst = (c == 1472) ? SU1 : SBB1;
        int jm = tid >> 2, q = tid & 3;
        const float* bp = B1 + jm * 512 + q * 128;
        const float* vp = vec + q * 128;
        float acc = 0.f;
        for (int cc = 0; cc < 128; ++cc)
            acc = fmaf(bp[cc], vp[cc], acc);
        sh[q][jm] = acc;
        __syncthreads();
        if (tid < 64)
            dst[tid] = (sh[0][tid] + sh[1][tid]) + (sh[2][tid] + sh[3][tid]);
    }
}

// ---------------------------------------------------------------------------
// gemmk: merged layer-1/2 GEMM, full-K (512), 64(M) x 64(N) tile, 4 waves.
// grid (10,64,1) = 640 blocks (same count/occupancy as the old split-K=2).
// bn<512 (C1 cols): fp32-complete values reduced IN-KERNEL to per-row
//   partials (sum, ssq, S1) -> Ps[bnIdx][row][3]. C1 never materialized
//   (deletes the 19 MB C1b/C2-partial round-trip).
// bn>=512 (C2 cols): hi+lo MFMA, fp32 single-plane C2 at ld 128.
// XOR-swizzled LDS (swizzle on global source idx; dest stays wave-uniform).
// ---------------------------------------------------------------------------
__global__ __launch_bounds__(256, 4) void gemmk(
        const unsigned short* __restrict__ Ah, const unsigned short* __restrict__ Al,
        const unsigned short* __restrict__ Wh,
        const float* __restrict__ g1, const float* __restrict__ B1,
        float* __restrict__ C2, float* __restrict__ Ps) {
    __shared__ __align__(16) unsigned short aH[4096];   // 64 x 64
    __shared__ __align__(16) unsigned short aL[4096];
    __shared__ __align__(16) unsigned short wHs[4096];  // 64 x 64
    const int tid = threadIdx.x;
    const int wv  = tid >> 6;
    const int ln  = tid & 63;
    const int lm  = ln & 15;
    const int lq  = ln >> 4;
    const int bm  = blockIdx.y * 64;
    const int bn  = blockIdx.x * 64;
    const bool alo = (bn >= 512);
    const int K = 512;

    f4 acc[4] = {};

    for (int kg = 0; kg < K; kg += 64) {
        __syncthreads();
        // A: 64 rows x 64 k = 512 granules, 2 per thread
#pragma unroll
        for (int i = 0; i < 2; ++i) {
            int slot = i * 256 + wv * 64 + ln;
            int row  = slot >> 3;
            int ch   = (slot & 7) ^ (row & 7);
            size_t go = (size_t)(bm + row) * K + kg + ch * 8;
            async16(Ah + go, aH + slot * 8);
            if (alo) async16(Al + go, aL + slot * 8);
        }
        // W: 64 rows x 64 k = 512 granules, 2 per thread
#pragma unroll
        for (int i = 0; i < 2; ++i) {
            int slot = i * 256 + wv * 64 + ln;
            int row  = slot >> 3;
            int ch   = (slot & 7) ^ (row & 7);
            size_t go = (size_t)(bn + row) * K + kg + ch * 8;
            async16(Wh + go, wHs + slot * 8);
        }
        __syncthreads();

#pragma unroll
        for (int kk = 0; kk < 2; ++kk) {
            const int ck = kk * 4 + lq;          // 16B chunk index in k
            bf8 a_h, a_l, b_h[4];
            {
                int r = wv * 16 + lm;            // wave owns 16 rows
                a_h = *(const bf8*)(aH + r * 64 + ((ck ^ (r & 7)) * 8));
                if (alo)
                    a_l = *(const bf8*)(aL + r * 64 + ((ck ^ (r & 7)) * 8));
            }
#pragma unroll
            for (int u = 0; u < 4; ++u) {
                int rb = u * 16 + lm;
                b_h[u] = *(const bf8*)(wHs + rb * 64 + ((ck ^ (rb & 7)) * 8));
            }
#pragma unroll
            for (int u = 0; u < 4; ++u) {
                acc[u] = __builtin_amdgcn_mfma_f32_16x16x32_bf16(a_h, b_h[u], acc[u], 0, 0, 0);
                if (alo)
                    acc[u] = __builtin_amdgcn_mfma_f32_16x16x32_bf16(a_l, b_h[u], acc[u], 0, 0, 0);
            }
        }
    }

    // C/D layout (verified): col = lane&15, row = quad*4 + reg
    if (bn < 512) {
        // reduce this 64-col tile into per-row (sum, ssq, S1) partials
        float s0a[4] = {0.f, 0.f, 0.f, 0.f};
        float q0a[4] = {0.f, 0.f, 0.f, 0.f};
        float s1a[4] = {0.f, 0.f, 0.f, 0.f};
#pragma unroll
        for (int u = 0; u < 4; ++u) {
            int col = bn + u * 16 + lm;
            float gv = g1[col];
#pragma unroll
            for (int r = 0; r < 4; ++r) {
                float y = acc[u][r];
                int jm = (bm + wv * 16 + lq * 4 + r) & 63;
                s0a[r] += y;
                q0a[r] = fmaf(y, y, q0a[r]);
                s1a[r] = fmaf(y, gv * B1[jm * 512 + col], s1a[r]);
            }
        }
#pragma unroll
        for (int m = 1; m < 16; m <<= 1) {
#pragma unroll
            for (int r = 0; r < 4; ++r) {
                s0a[r] += __shfl_xor(s0a[r], m, 64);
                q0a[r] += __shfl_xor(q0a[r], m, 64);
                s1a[r] += __shfl_xor(s1a[r], m, 64);
            }
        }
        if (lm == 0) {
#pragma unroll
            for (int r = 0; r < 4; ++r) {
                int row = bm + wv * 16 + lq * 4 + r;
                size_t pb = ((size_t)blockIdx.x * ROWS + row) * 3;
                Ps[pb]     = s0a[r];
                Ps[pb + 1] = q0a[r];
                Ps[pb + 2] = s1a[r];
            }
        }
    } else {
#pragma unroll
        for (int u = 0; u < 4; ++u) {
            int row = bm + wv * 16 + lq * 4;
            int col = bn + u * 16 + lm;
#pragma unroll
            for (int r = 0; r < 4; ++r)
                C2[(size_t)(row + r) * 128 + (col - 512)] = acc[u][r];
        }
    }
}

// ---------------------------------------------------------------------------
// ptk: one row per wave. Sum 8 Ps partials -> (sum, ssq, S1);
// p = rstd*(S1 - mean*SU1[jm]) + SBB1[jm].
// Then t = LN64(C2y + p*G2y[jm]), rsum = C2r + p*G2r[jm].
// ---------------------------------------------------------------------------
__global__ __launch_bounds__(256) void ptk(
        const float* __restrict__ Ps, const float* __restrict__ C2,
        const float* __restrict__ g2, const float* __restrict__ b2,
        const float* __restrict__ G2y, const float* __restrict__ G2r,
        const float* __restrict__ SU1, const float* __restrict__ SBB1,
        float* __restrict__ t, float* __restrict__ rsum) {
    const int row = blockIdx.x * 4 + (threadIdx.x >> 6);
    const int l = threadIdx.x & 63;
    const int jm = row & 63;
    float sum = 0.f, ssq = 0.f, S1 = 0.f;
#pragma unroll
    for (int bn = 0; bn < 8; ++bn) {
        const float* pp = Ps + ((size_t)bn * ROWS + row) * 3;
        sum += pp[0]; ssq += pp[1]; S1 += pp[2];
    }
    float mean = sum * (1.0f / 512.0f);
    float var  = ssq * (1.0f / 512.0f) - mean * mean;
    float rstd = rsqrtf(var + 1e-5f);
    float p = rstd * (S1 - mean * SU1[jm]) + SBB1[jm];

    float v  = C2[(size_t)row * 128 + l]      + p * G2y[jm * 64 + l];
    float rv = C2[(size_t)row * 128 + 64 + l] + p * G2r[jm * 64 + l];
    float s2 = v, q2 = v * v;
#pragma unroll
    for (int m = 1; m < 64; m <<= 1) {
        s2 += __shfl_xor(s2, m, 64);
        q2 += __shfl_xor(q2, m, 64);
    }
    float mean2 = s2 * (1.0f / 64.0f);
    float var2  = q2 * (1.0f / 64.0f) - mean2 * mean2;
    float rstd2 = rsqrtf(var2 + 1e-5f);
    t[row * 64 + l]    = (v - mean2) * rstd2 * g2[l] + b2[l];
    rsum[row * 64 + l] = rv;
}

// ---------------------------------------------------------------------------
// tsk2: Chebyshev-recurrence TS layer (verified).
// ---------------------------------------------------------------------------
__global__ __launch_bounds__(256) void tsk2(
        const float* __restrict__ t, const float* __restrict__ rsum,
        const float* __restrict__ P,
        unsigned short* __restrict__ Hh, unsigned short* __restrict__ Hl) {
    const int bid = blockIdx.x;
    const int i   = bid >> 3;
    const int sg  = bid & 7;
    const int w   = threadIdx.x >> 6;
    const int ln  = threadIdx.x & 63;       // j
    const int s0  = sg * 256 + w * 64;
    const int idx = i * 64 + ln;
    const float* pp = P + idx * 8;
    const float sf0 = (float)s0;

    float k2c[8], ca[8], cb[8];
#pragma unroll
    for (int g = 0; g < 8; ++g) {
        float pf   = (float)(idx * 8 + g + 2);
        float invp = __builtin_amdgcn_rcpf(pf);
        k2c[g] = 2.0f * __builtin_amdgcn_cosf(invp);     // 2*cos(2*pi/p)
        float q0 = floorf(sf0 * invp);
        float r0 = fmaf(-q0, pf, sf0);
        float f0 = r0 * invp; f0 -= floorf(f0);
        float c0 = __builtin_amdgcn_cosf(f0);
        float sf1 = sf0 + 1.0f;
        float q1 = floorf(sf1 * invp);
        float r1 = fmaf(-q1, pf, sf1);
        float f1 = r1 * invp; f1 -= floorf(f1);
        float c1 = __builtin_amdgcn_cosf(f1);
        float Pv = pp[g];
        ca[g] = Pv * c0;
        cb[g] = Pv * c1;
    }

    const int tb = s0 * 64 + ln;
    float t0c = t[tb], t1c = t[131072 + tb];
    float res0 = 0.f, res1 = 0.f;

    for (int st = 0; st < 64; st += 2) {
        float t0n  = t[tb + (st + 1) * 64];
        float t1n  = t[131072 + tb + (st + 1) * 64];
        float ws = ((ca[0] + ca[1]) + (ca[2] + ca[3]))
                 + ((ca[4] + ca[5]) + (ca[6] + ca[7]));
#pragma unroll
        for (int g = 0; g < 8; ++g) ca[g] = fmaf(k2c[g], cb[g], -ca[g]);
        float v0 = ws * t0c, v1 = ws * t1c;
#pragma unroll
        for (int m = 1; m < 64; m <<= 1) {
            v0 += __shfl_xor(v0, m, 64);
            v1 += __shfl_xor(v1, m, 64);
        }
        res0 = (ln == st) ? v0 : res0;
        res1 = (ln == st) ? v1 : res1;
        float t0n2 = t[tb + (st + 2) * 64];
        float t1n2 = t[131072 + tb + (st + 2) * 64];
        float ws2 = ((cb[0] + cb[1]) + (cb[2] + cb[3]))
                  + ((cb[4] + cb[5]) + (cb[6] + cb[7]));
#pragma unroll
        for (int g = 0; g < 8; ++g) cb[g] = fmaf(k2c[g], ca[g], -cb[g]);
        float v0b = ws2 * t0n, v1b = ws2 * t1n;
#pragma unroll
        for (int m = 1; m < 64; m <<= 1) {
            v0b += __shfl_xor(v0b, m, 64);
            v1b += __shfl_xor(v1b, m, 64);
        }
        res0 = (ln == st + 1) ? v0b : res0;
        res1 = (ln == st + 1) ? v1b : res1;
        t0c = t0n2; t1c = t1n2;
    }

    const int s = s0 + ln;
    {
        float v = res0 + rsum[(size_t)s * 64 + i];
        unsigned short h, l; hilo(v, h, l);
        Hh[(size_t)s * 64 + i] = h; Hl[(size_t)s * 64 + i] = l;
        float v1e = res1 + rsum[(size_t)(SEQ + s) * 64 + i];
        hilo(v1e, h, l);
        Hh[(size_t)(SEQ + s) * 64 + i] = h; Hl[(size_t)(SEQ + s) * 64 + i] = l;
    }
}

// ---------------------------------------------------------------------------
// g3ln: fused layer-3 GEMM + LN + rank-1 RN + residual + output (R4-verified,
// best-measured layer-3 variant).
// ---------------------------------------------------------------------------
__global__ __launch_bounds__(256) void g3ln(
        const unsigned short* __restrict__ Hh, const unsigned short* __restrict__ Hl,
        const unsigned short* __restrict__ Wc3h,   // [1024][64] bf16 (W3;R3)
        const float* __restrict__ g3, const float* __restrict__ b3,
        const float* __restrict__ B3, const float* __restrict__ A3T,
        float* __restrict__ outf) {
    __shared__ __align__(16) unsigned short aH[1024];   // 16 x 64 hi
    __shared__ __align__(16) unsigned short aL[1024];   // 16 x 64 lo
    __shared__ __align__(16) unsigned short wS[16384];  // 256 x 64 (one phase)
    __shared__ float cS[16 * 1024];                     // 64 KB C tile
    const int tid = threadIdx.x;
    const int wv  = tid >> 6;
    const int ln  = tid & 63;
    const int lm  = ln & 15;
    const int lq  = ln >> 4;
    const int r0  = blockIdx.x * 16;

    // stage A (h2 rows r0..r0+15): waves 0,1 -> hi slots 0..127; 2,3 -> lo
    {
        int slot = (wv & 1) * 64 + ln;
        int row  = slot >> 3;
        int ch   = (slot & 7) ^ (row & 7);
        size_t go = (size_t)(r0 + row) * 64 + ch * 8;
        if (wv < 2) async16(Hh + go, aH + slot * 8);
        else        async16(Hl + go, aL + slot * 8);
    }

    bf8 ah[2], al[2];
    for (int q = 0; q < 4; ++q) {
        // stage W phase q: local rows lr 0..255 -> W row (lr>>6)*256 + q*64 + (lr&63)
#pragma unroll
        for (int i = 0; i < 8; ++i) {
            int slot = i * 256 + tid;
            int lr   = slot >> 3;
            int ch   = (slot & 7) ^ (lr & 7);
            int grow = (lr >> 6) * 256 + q * 64 + (lr & 63);
            size_t go = (size_t)grow * 64 + ch * 8;
            async16(Wc3h + go, wS + slot * 8);
        }
        __syncthreads();   // drains vmcnt: A (q==0) + W_q staged
        if (q == 0) {
#pragma unroll
            for (int kk = 0; kk < 2; ++kk) {
                int ck = kk * 4 + lq;
                ah[kk] = *(const bf8*)(aH + lm * 64 + ((ck ^ (lm & 7)) * 8));
                al[kk] = *(const bf8*)(aL + lm * 64 + ((ck ^ (lm & 7)) * 8));
            }
        }
        f4 acc[4] = {};
#pragma unroll
        for (int kk = 0; kk < 2; ++kk) {
            int ck = kk * 4 + lq;
            bf8 bh[4];
#pragma unroll
            for (int u = 0; u < 4; ++u) {
                int lr = wv * 64 + u * 16 + lm;
                bh[u] = *(const bf8*)(wS + lr * 64 + ((ck ^ (lr & 7)) * 8));
            }
#pragma unroll
            for (int u = 0; u < 4; ++u) {
                acc[u] = __builtin_amdgcn_mfma_f32_16x16x32_bf16(ah[kk], bh[u], acc[u], 0, 0, 0);
                acc[u] = __builtin_amdgcn_mfma_f32_16x16x32_bf16(al[kk], bh[u], acc[u], 0, 0, 0);
            }
        }
        // C/D layout: col = u*16 + lm (+ wave/phase base), row = lq*4 + r
#pragma unroll
        for (int u = 0; u < 4; ++u) {
            int col = wv * 256 + q * 64 + u * 16 + lm;
#pragma unroll
            for (int r = 0; r < 4; ++r)
                cS[(lq * 4 + r) * 1024 + col] = acc[u][r];
        }
        __syncthreads();   // wS reuse + cS visibility
    }

    // epilogue: wave wv owns rows wv*4 .. wv*4+3
    for (int rr = 0; rr < 4; ++rr) {
        int row  = wv * 4 + rr;
        int grow = r0 + row;
        int jm   = grow & 63;
        const float* Bp = B3  + jm * 512;
        const float* Ap = A3T + jm * 512;
        float sum = 0.f, ssq = 0.f, S1 = 0.f, SU = 0.f, SBB = 0.f;
#pragma unroll
        for (int k = 0; k < 8; ++k) {
            int col = ln + k * 64;
            float y  = cS[row * 1024 + col];
            float Bv = Bp[col];
            float gv = g3[col];
            float bv = b3[col];
            float u = gv * Bv;
            sum += y;
            ssq = fmaf(y, y, ssq);
            S1  = fmaf(y, u, S1);
            SU  += u;
            SBB = fmaf(bv, Bv, SBB);
        }
#pragma unroll
        for (int m = 1; m < 64; m <<= 1) {
            sum += __shfl_xor(sum, m, 64);
            ssq += __shfl_xor(ssq, m, 64);
            S1  += __shfl_xor(S1, m, 64);
            SU  += __shfl_xor(SU, m, 64);
            SBB += __shfl_xor(SBB, m, 64);
        }
        float mean = sum * (1.0f / 512.0f);
        float var  = ssq * (1.0f / 512.0f) - mean * mean;
        float rstd = rsqrtf(var + 1e-5f);
        float p = rstd * (S1 - mean * SU) + SBB;
#pragma unroll
        for (int k = 0; k < 8; ++k) {
            int col = ln + k * 64;
            float res = cS[row * 1024 + 512 + col];
            outf[(size_t)grow * 512 + col] = fmaf(p, Ap[col], res);
        }
    }
}

// ---------------------------------------------------------------------------
extern "C" void kernel_launch(void* const* d_in, const int* in_sizes, int n_in,
                              void* d_out, int out_size, void* d_ws, size_t ws_size,
                              hipStream_t stream) {
    (void)in_sizes; (void)n_in; (void)out_size; (void)ws_size;
    const float* x  = (const float*)d_in[0];
    const float* W1 = (const float*)d_in[1];
    const float* g1 = (const float*)d_in[2];
    const float* b1 = (const float*)d_in[3];
    const float* A1 = (const float*)d_in[4];
    const float* B1 = (const float*)d_in[5];
    const float* M2 = (const float*)d_in[6];
    const float* g2 = (const float*)d_in[7];
    const float* b2 = (const float*)d_in[8];
    const float* P2 = (const float*)d_in[9];
    const float* R2 = (const float*)d_in[10];
    const float* W3 = (const float*)d_in[11];
    const float* g3 = (const float*)d_in[12];
    const float* b3 = (const float*)d_in[13];
    const float* A3 = (const float*)d_in[14];
    const float* B3 = (const float*)d_in[15];
    const float* R3 = (const float*)d_in[16];

    float* ws = (float*)d_ws;
    float* C2   = ws;                  // 524,288 fp32 (y|res, ld 128, full-K)
    float* Ps   = ws + 524288;         // 98,304 (8 x 4096 x 3 row partials)
    float* t    = ws + 4194304;        // 262,144
    float* rsum = ws + 4456448;        // 262,144 (must follow t: overrun pad)
    float* G2y  = ws + 4718592;        // 4,096
    float* G2r  = ws + 4722688;        // 4,096
    float* SU1  = ws + 4726784;        // 64
    float* SBB1 = ws + 4726912;        // 64
    float* A3T  = ws + 4751360;        // 32,768
    unsigned short* us = (unsigned short*)(ws + 4784128);
    unsigned short* xh   = us;                  // 2,097,152
    unsigned short* xl   = us + 2097152;        // 2,097,152
    unsigned short* W1h  = us + 6291456;        // 262,144 (rows 0..511 of Wbig)
    unsigned short* Wc2h = us + 6553600;        // 65,536  (rows 512..639 of Wbig)
    unsigned short* Wc3h = us + 6619136;        // 65,536 (1024 x 64)
    unsigned short* h2h  = us + 6684672;        // 262,144
    unsigned short* h2l  = us + 6946816;        // 262,144

    dim3 blk(256);

    // 0) convert x (hi+lo) + weights (hi) + A3 transpose + G2y/G2r + SU1/SBB1
    convk<<<1474, blk, 0, stream>>>(x, W1, M2, R2, W3, R3, A1, A3, g1, b1, B1,
                                    xh, xl, W1h, Wc2h, Wc3h, A3T,
                                    G2y, G2r, SU1, SBB1);

    // 1) merged GEMM, full-K: C1 cols reduced in-kernel to Ps; C2 cols -> C2
    gemmk<<<dim3(10, 64, 1), blk, 0, stream>>>(xh, xl, W1h, g1, B1, C2, Ps);

    // 2) p from Ps partials; t = LN64(C2y + p*G2y); rsum = C2r + p*G2r
    ptk<<<1024, blk, 0, stream>>>(Ps, C2, g2, b2, G2y, G2r, SU1, SBB1, t, rsum);

    // 3) TS Chebyshev recurrence -> h2 (hi/lo)
    tsk2<<<512, blk, 0, stream>>>(t, rsum, P2, h2h, h2l);

    // 4) fused layer-3: GEMM(K=64, hi+lo) + LN + rank-1 + residual -> out
    g3ln<<<256, blk, 0, stream>>>(h2h, h2l, Wc3h, g3, b3, B3, A3T, (float*)d_out);
}

// Round 10
// 143.123 us; speedup vs baseline: 1.0308x; 1.0308x over previous
//
#include <hip/hip_runtime.h>
#include <math.h>

#define SEQ  2048
#define ROWS 4096
#define D0   512
#define D1   64
#define C2S  524288

typedef short bf8 __attribute__((ext_vector_type(8)));   // 8 bf16 = 4 VGPRs
typedef float f4  __attribute__((ext_vector_type(4)));   // MFMA acc

// fp32 -> bf16 (RNE) and hi/lo split
__device__ __forceinline__ unsigned short f2bf(float f) {
    unsigned u = __float_as_uint(f);
    return (unsigned short)((u + 0x7fffu + ((u >> 16) & 1u)) >> 16);
}
__device__ __forceinline__ float bf2f(unsigned short u) {
    return __uint_as_float((unsigned)u << 16);
}
__device__ __forceinline__ void hilo(float f, unsigned short& h, unsigned short& l) {
    h = f2bf(f);
    float fh = bf2f(h);
    l = f2bf(f - fh);
}
__device__ __forceinline__ void cv4h(unsigned short* dh, int idx, float4 v) {
    ushort4 hv;
    hv.x = f2bf(v.x); hv.y = f2bf(v.y); hv.z = f2bf(v.z); hv.w = f2bf(v.w);
    *(ushort4*)(dh + idx) = hv;
}

// async global->LDS 16B (dest = wave-uniform base + lane*16)
__device__ __forceinline__ void async16(const void* g, void* l) {
    __builtin_amdgcn_global_load_lds(
        (const __attribute__((address_space(1))) unsigned int*)g,
        (__attribute__((address_space(3))) unsigned int*)l, 16, 0, 0);
}

// ---------------------------------------------------------------------------
// convk: x -> xh+xl (hi/lo); weights -> bf16 hi; A3 transpose;
// G2y[jm,j] = sum_c A1[c,jm]*M2[j,c]; G2r[jm,i] = sum_c A1[c,jm]*R2[i,c].
// ---------------------------------------------------------------------------
__global__ __launch_bounds__(256) void convk(
        const float* __restrict__ x,  const float* __restrict__ W1,
        const float* __restrict__ M2, const float* __restrict__ R2,
        const float* __restrict__ W3, const float* __restrict__ R3,
        const float* __restrict__ A1, const float* __restrict__ A3,
        unsigned short* __restrict__ xh, unsigned short* __restrict__ xl,
        unsigned short* __restrict__ W1h,    // head of 640-row Wbig region
        unsigned short* __restrict__ C2h,    // rows 512..639 of Wbig (M2;R2)
        unsigned short* __restrict__ C3h,
        float* __restrict__ A3T,
        float* __restrict__ G2y, float* __restrict__ G2r) {
    __shared__ float sh[4][64];
    int c = blockIdx.x, tid = threadIdx.x;
    if (c < 1024) {
        int base = c * 2048 + tid * 4;
        float4 v0 = *(const float4*)(x + base);
        float4 v1 = *(const float4*)(x + base + 1024);
        ushort4 h, l;
        hilo(v0.x, h.x, l.x); hilo(v0.y, h.y, l.y);
        hilo(v0.z, h.z, l.z); hilo(v0.w, h.w, l.w);
        *(ushort4*)(xh + base) = h; *(ushort4*)(xl + base) = l;
        hilo(v1.x, h.x, l.x); hilo(v1.y, h.y, l.y);
        hilo(v1.z, h.z, l.z); hilo(v1.w, h.w, l.w);
        *(ushort4*)(xh + base + 1024) = h; *(ushort4*)(xl + base + 1024) = l;
    } else if (c < 1216) {
        const float* src; unsigned short* dh; int off;
        if      (c < 1152) { src = W1; dh = W1h;         off = c - 1024; }
        else if (c < 1168) { src = M2; dh = C2h;         off = c - 1152; }
        else if (c < 1184) { src = R2; dh = C2h + 32768; off = c - 1168; }
        else if (c < 1200) { src = W3; dh = C3h;         off = c - 1184; }
        else               { src = R3; dh = C3h + 32768; off = c - 1200; }
        int base = off * 2048 + tid * 4;
        cv4h(dh, base,        *(const float4*)(src + base));
        cv4h(dh, base + 1024, *(const float4*)(src + base + 1024));
    } else if (c < 1344) {
        int gid = (c - 1216) * 256 + tid;     // 0..32767
        int i = gid >> 6, j = gid & 63;       // A3 (512 x 64)
        A3T[j * 512 + i] = A3[gid];
    } else {
        // G blocks: 1344..1407 -> G2y rows j; 1408..1471 -> G2r rows i
        int jrow = (c - 1344) & 63;
        const float* wv = (c < 1408) ? (M2 + jrow * 512) : (R2 + jrow * 512);
        float* G = (c < 1408) ? G2y : G2r;
        int jm = tid & 63, q = tid >> 6;
        const float* ap = A1 + (q * 128) * 64 + jm;
        const float* wp = wv + q * 128;
        float acc = 0.f;
        for (int cc = 0; cc < 128; ++cc)
            acc = fmaf(ap[cc * 64], wp[cc], acc);
        sh[q][jm] = acc;
        __syncthreads();
        if (tid < 64)
            G[tid * 64 + jrow] = (sh[0][tid] + sh[1][tid]) + (sh[2][tid] + sh[3][tid]);
    }
}

// ---------------------------------------------------------------------------
// gemmw: merged layer-1/2 GEMM, 64(M) x 128(N) tile, BK=64, 256 thr = 4 waves.
// Wide-N tile halves A re-reads (5 bn-tiles vs 10); M=64 keeps 640 blocks
// (balanced 2.5/CU). A-lo plane only for bn=512 tile (LN-direct cols).
// Split-K partials: col<512 bf16 at ld 512, col>=512 fp32 at ld 128.
// XOR-swizzled LDS (swizzle on global source idx; dest stays wave-uniform).
// ---------------------------------------------------------------------------
__global__ __launch_bounds__(256, 3) void gemmw(
        const unsigned short* __restrict__ Ah, const unsigned short* __restrict__ Al,
        const unsigned short* __restrict__ Wh,
        float* __restrict__ Cf, unsigned short* __restrict__ Cb,
        int K, int Ks) {
    __shared__ __align__(16) unsigned short aH[4096];   // 64 x 64
    __shared__ __align__(16) unsigned short aL[4096];
    __shared__ __align__(16) unsigned short wHs[8192];  // 128 x 64
    const int tid = threadIdx.x;
    const int wv  = tid >> 6;
    const int ln  = tid & 63;
    const int lm  = ln & 15;
    const int lq  = ln >> 4;
    const int bm  = blockIdx.y * 64;
    const int bn  = blockIdx.x * 128;
    const int k0  = blockIdx.z * Ks;
    const bool alo = (bn >= 512);

    f4 acc[8] = {};

    for (int kt = 0; kt < Ks; kt += 64) {
        const int kg = k0 + kt;
        __syncthreads();
        // A: 64 rows x 64 k = 512 granules, 2 per thread
#pragma unroll
        for (int i = 0; i < 2; ++i) {
            int slot = i * 256 + wv * 64 + ln;
            int row  = slot >> 3;
            int ch   = (slot & 7) ^ (row & 7);
            size_t go = (size_t)(bm + row) * K + kg + ch * 8;
            async16(Ah + go, aH + slot * 8);
            if (alo) async16(Al + go, aL + slot * 8);
        }
        // W: 128 rows x 64 k = 1024 granules, 4 per thread
#pragma unroll
        for (int i = 0; i < 4; ++i) {
            int slot = i * 256 + wv * 64 + ln;
            int row  = slot >> 3;
            int ch   = (slot & 7) ^ (row & 7);
            size_t go = (size_t)(bn + row) * K + kg + ch * 8;
            async16(Wh + go, wHs + slot * 8);
        }
        __syncthreads();

#pragma unroll
        for (int kk = 0; kk < 2; ++kk) {
            const int ck = kk * 4 + lq;          // 16B chunk index in k
            bf8 a_h, a_l, b_h[8];
            {
                int r = wv * 16 + lm;            // wave owns 16 rows
                a_h = *(const bf8*)(aH + r * 64 + ((ck ^ (r & 7)) * 8));
                if (alo)
                    a_l = *(const bf8*)(aL + r * 64 + ((ck ^ (r & 7)) * 8));
            }
#pragma unroll
            for (int u = 0; u < 8; ++u) {
                int rb = u * 16 + lm;
                b_h[u] = *(const bf8*)(wHs + rb * 64 + ((ck ^ (rb & 7)) * 8));
            }
#pragma unroll
            for (int u = 0; u < 8; ++u) {
                acc[u] = __builtin_amdgcn_mfma_f32_16x16x32_bf16(a_h, b_h[u], acc[u], 0, 0, 0);
                if (alo)
                    acc[u] = __builtin_amdgcn_mfma_f32_16x16x32_bf16(a_l, b_h[u], acc[u], 0, 0, 0);
            }
        }
    }

    // C/D layout (verified): col = lane&15, row = quad*4 + reg
#pragma unroll
    for (int u = 0; u < 8; ++u) {
        int row = bm + wv * 16 + lq * 4;
        int col = bn + u * 16 + lm;
#pragma unroll
        for (int r = 0; r < 4; ++r) {
            float v = acc[u][r];
            if (col < 512)
                Cb[(size_t)blockIdx.z * ROWS * 512 + (size_t)(row + r) * 512 + col] = f2bf(v);
            else
                Cf[(size_t)blockIdx.z * ROWS * 128 + (size_t)(row + r) * 128 + (col - 512)] = v;
        }
    }
}

// ---------------------------------------------------------------------------
// ptk: one row per wave. From C1 partials (bf16 x2): row reduces ->
// p = rstd*(S1 - mean*SU) + SBB. Then t = LN64(C2y + p*G2y[jm]),
// rsum = C2r + p*G2r[jm].
// ---------------------------------------------------------------------------
__global__ __launch_bounds__(256) void ptk(
        const unsigned short* __restrict__ C1b,   // 2 planes ROWS x 512 bf16
        const float* __restrict__ C2,             // 2 planes ROWS x 128 fp32
        const float* __restrict__ B1,
        const float* __restrict__ g1, const float* __restrict__ b1,
        const float* __restrict__ g2, const float* __restrict__ b2,
        const float* __restrict__ G2y, const float* __restrict__ G2r,
        float* __restrict__ t, float* __restrict__ rsum) {
    const int row = blockIdx.x * 4 + (threadIdx.x >> 6);
    const int l = threadIdx.x & 63;
    const int c = l * 8;
    const int jm = row & 63;
    const size_t rb0 = (size_t)row * 512 + c;
    ushort4 ua = *(const ushort4*)(C1b + rb0);
    ushort4 ub = *(const ushort4*)(C1b + rb0 + 4);
    ushort4 va = *(const ushort4*)(C1b + (size_t)ROWS * 512 + rb0);
    ushort4 vb = *(const ushort4*)(C1b + (size_t)ROWS * 512 + rb0 + 4);
    float y[8];
    y[0] = bf2f(ua.x) + bf2f(va.x); y[1] = bf2f(ua.y) + bf2f(va.y);
    y[2] = bf2f(ua.z) + bf2f(va.z); y[3] = bf2f(ua.w) + bf2f(va.w);
    y[4] = bf2f(ub.x) + bf2f(vb.x); y[5] = bf2f(ub.y) + bf2f(vb.y);
    y[6] = bf2f(ub.z) + bf2f(vb.z); y[7] = bf2f(ub.w) + bf2f(vb.w);
    float4 B0  = *(const float4*)(B1 + jm * 512 + c);
    float4 B1q = *(const float4*)(B1 + jm * 512 + c + 4);
    float4 gg0 = *(const float4*)(g1 + c), gg1 = *(const float4*)(g1 + c + 4);
    float4 bb0 = *(const float4*)(b1 + c), bb1 = *(const float4*)(b1 + c + 4);
    float Bv[8] = {B0.x, B0.y, B0.z, B0.w, B1q.x, B1q.y, B1q.z, B1q.w};
    float gv[8] = {gg0.x, gg0.y, gg0.z, gg0.w, gg1.x, gg1.y, gg1.z, gg1.w};
    float bv[8] = {bb0.x, bb0.y, bb0.z, bb0.w, bb1.x, bb1.y, bb1.z, bb1.w};
    float sum = 0.f, ssq = 0.f, S1 = 0.f, SU = 0.f, SBB = 0.f;
#pragma unroll
    for (int i = 0; i < 8; ++i) {
        float u = gv[i] * Bv[i];
        sum += y[i];
        ssq = fmaf(y[i], y[i], ssq);
        S1  = fmaf(y[i], u, S1);
        SU  += u;
        SBB = fmaf(bv[i], Bv[i], SBB);
    }
#pragma unroll
    for (int m = 1; m < 64; m <<= 1) {
        sum += __shfl_xor(sum, m, 64);
        ssq += __shfl_xor(ssq, m, 64);
        S1  += __shfl_xor(S1, m, 64);
        SU  += __shfl_xor(SU, m, 64);
        SBB += __shfl_xor(SBB, m, 64);
    }
    float mean = sum * (1.0f / 512.0f);
    float var  = ssq * (1.0f / 512.0f) - mean * mean;
    float rstd = rsqrtf(var + 1e-5f);
    float p = rstd * (S1 - mean * SU) + SBB;

    const size_t rb = (size_t)row * 128;
    float z  = C2[rb + l]      + C2[C2S + rb + l];
    float zr = C2[rb + 64 + l] + C2[C2S + rb + 64 + l];
    float v  = z  + p * G2y[jm * 64 + l];
    float rv = zr + p * G2r[jm * 64 + l];
    float s2 = v, q2 = v * v;
#pragma unroll
    for (int m = 1; m < 64; m <<= 1) {
        s2 += __shfl_xor(s2, m, 64);
        q2 += __shfl_xor(q2, m, 64);
    }
    float mean2 = s2 * (1.0f / 64.0f);
    float var2  = q2 * (1.0f / 64.0f) - mean2 * mean2;
    float rstd2 = rsqrtf(var2 + 1e-5f);
    t[row * 64 + l]    = (v - mean2) * rstd2 * g2[l] + b2[l];
    rsum[row * 64 + l] = rv;
}

// ---------------------------------------------------------------------------
// tsk2: Chebyshev-recurrence TS layer (verified).
// ---------------------------------------------------------------------------
__global__ __launch_bounds__(256) void tsk2(
        const float* __restrict__ t, const float* __restrict__ rsum,
        const float* __restrict__ P,
        unsigned short* __restrict__ Hh, unsigned short* __restrict__ Hl) {
    const int bid = blockIdx.x;
    const int i   = bid >> 3;
    const int sg  = bid & 7;
    const int w   = threadIdx.x >> 6;
    const int ln  = threadIdx.x & 63;       // j
    const int s0  = sg * 256 + w * 64;
    const int idx = i * 64 + ln;
    const float* pp = P + idx * 8;
    const float sf0 = (float)s0;

    float k2c[8], ca[8], cb[8];
#pragma unroll
    for (int g = 0; g < 8; ++g) {
        float pf   = (float)(idx * 8 + g + 2);
        float invp = __builtin_amdgcn_rcpf(pf);
        k2c[g] = 2.0f * __builtin_amdgcn_cosf(invp);     // 2*cos(2*pi/p)
        float q0 = floorf(sf0 * invp);
        float r0 = fmaf(-q0, pf, sf0);
        float f0 = r0 * invp; f0 -= floorf(f0);
        float c0 = __builtin_amdgcn_cosf(f0);
        float sf1 = sf0 + 1.0f;
        float q1 = floorf(sf1 * invp);
        float r1 = fmaf(-q1, pf, sf1);
        float f1 = r1 * invp; f1 -= floorf(f1);
        float c1 = __builtin_amdgcn_cosf(f1);
        float Pv = pp[g];
        ca[g] = Pv * c0;
        cb[g] = Pv * c1;
    }

    const int tb = s0 * 64 + ln;
    float t0c = t[tb], t1c = t[131072 + tb];
    float res0 = 0.f, res1 = 0.f;

    for (int st = 0; st < 64; st += 2) {
        float t0n  = t[tb + (st + 1) * 64];
        float t1n  = t[131072 + tb + (st + 1) * 64];
        float ws = ((ca[0] + ca[1]) + (ca[2] + ca[3]))
                 + ((ca[4] + ca[5]) + (ca[6] + ca[7]));
#pragma unroll
        for (int g = 0; g < 8; ++g) ca[g] = fmaf(k2c[g], cb[g], -ca[g]);
        float v0 = ws * t0c, v1 = ws * t1c;
#pragma unroll
        for (int m = 1; m < 64; m <<= 1) {
            v0 += __shfl_xor(v0, m, 64);
            v1 += __shfl_xor(v1, m, 64);
        }
        res0 = (ln == st) ? v0 : res0;
        res1 = (ln == st) ? v1 : res1;
        float t0n2 = t[tb + (st + 2) * 64];
        float t1n2 = t[131072 + tb + (st + 2) * 64];
        float ws2 = ((cb[0] + cb[1]) + (cb[2] + cb[3]))
                  + ((cb[4] + cb[5]) + (cb[6] + cb[7]));
#pragma unroll
        for (int g = 0; g < 8; ++g) cb[g] = fmaf(k2c[g], ca[g], -cb[g]);
        float v0b = ws2 * t0n, v1b = ws2 * t1n;
#pragma unroll
        for (int m = 1; m < 64; m <<= 1) {
            v0b += __shfl_xor(v0b, m, 64);
            v1b += __shfl_xor(v1b, m, 64);
        }
        res0 = (ln == st + 1) ? v0b : res0;
        res1 = (ln == st + 1) ? v1b : res1;
        t0c = t0n2; t1c = t1n2;
    }

    const int s = s0 + ln;
    {
        float v = res0 + rsum[(size_t)s * 64 + i];
        unsigned short h, l; hilo(v, h, l);
        Hh[(size_t)s * 64 + i] = h; Hl[(size_t)s * 64 + i] = l;
        float v1e = res1 + rsum[(size_t)(SEQ + s) * 64 + i];
        hilo(v1e, h, l);
        Hh[(size_t)(SEQ + s) * 64 + i] = h; Hl[(size_t)(SEQ + s) * 64 + i] = l;
    }
}

// ---------------------------------------------------------------------------
// g3ln: fused layer-3 GEMM + LN + rank-1 RN + residual + output (R4-verified,
// best-measured layer-3 variant: 143.7 us config).
// ---------------------------------------------------------------------------
__global__ __launch_bounds__(256) void g3ln(
        const unsigned short* __restrict__ Hh, const unsigned short* __restrict__ Hl,
        const unsigned short* __restrict__ Wc3h,   // [1024][64] bf16 (W3;R3)
        const float* __restrict__ g3, const float* __restrict__ b3,
        const float* __restrict__ B3, const float* __restrict__ A3T,
        float* __restrict__ outf) {
    __shared__ __align__(16) unsigned short aH[1024];   // 16 x 64 hi
    __shared__ __align__(16) unsigned short aL[1024];   // 16 x 64 lo
    __shared__ __align__(16) unsigned short wS[16384];  // 256 x 64 (one phase)
    __shared__ float cS[16 * 1024];                     // 64 KB C tile
    const int tid = threadIdx.x;
    const int wv  = tid >> 6;
    const int ln  = tid & 63;
    const int lm  = ln & 15;
    const int lq  = ln >> 4;
    const int r0  = blockIdx.x * 16;

    // stage A (h2 rows r0..r0+15): waves 0,1 -> hi slots 0..127; 2,3 -> lo
    {
        int slot = (wv & 1) * 64 + ln;
        int row  = slot >> 3;
        int ch   = (slot & 7) ^ (row & 7);
        size_t go = (size_t)(r0 + row) * 64 + ch * 8;
        if (wv < 2) async16(Hh + go, aH + slot * 8);
        else        async16(Hl + go, aL + slot * 8);
    }

    bf8 ah[2], al[2];
    for (int q = 0; q < 4; ++q) {
        // stage W phase q: local rows lr 0..255 -> W row (lr>>6)*256 + q*64 + (lr&63)
#pragma unroll
        for (int i = 0; i < 8; ++i) {
            int slot = i * 256 + tid;
            int lr   = slot >> 3;
            int ch   = (slot & 7) ^ (lr & 7);
            int grow = (lr >> 6) * 256 + q * 64 + (lr & 63);
            size_t go = (size_t)grow * 64 + ch * 8;
            async16(Wc3h + go, wS + slot * 8);
        }
        __syncthreads();   // drains vmcnt: A (q==0) + W_q staged
        if (q == 0) {
#pragma unroll
            for (int kk = 0; kk < 2; ++kk) {
                int ck = kk * 4 + lq;
                ah[kk] = *(const bf8*)(aH + lm * 64 + ((ck ^ (lm & 7)) * 8));
                al[kk] = *(const bf8*)(aL + lm * 64 + ((ck ^ (lm & 7)) * 8));
            }
        }
        f4 acc[4] = {};
#pragma unroll
        for (int kk = 0; kk < 2; ++kk) {
            int ck = kk * 4 + lq;
            bf8 bh[4];
#pragma unroll
            for (int u = 0; u < 4; ++u) {
                int lr = wv * 64 + u * 16 + lm;
                bh[u] = *(const bf8*)(wS + lr * 64 + ((ck ^ (lr & 7)) * 8));
            }
#pragma unroll
            for (int u = 0; u < 4; ++u) {
                acc[u] = __builtin_amdgcn_mfma_f32_16x16x32_bf16(ah[kk], bh[u], acc[u], 0, 0, 0);
                acc[u] = __builtin_amdgcn_mfma_f32_16x16x32_bf16(al[kk], bh[u], acc[u], 0, 0, 0);
            }
        }
        // C/D layout: col = u*16 + lm (+ wave/phase base), row = lq*4 + r
#pragma unroll
        for (int u = 0; u < 4; ++u) {
            int col = wv * 256 + q * 64 + u * 16 + lm;
#pragma unroll
            for (int r = 0; r < 4; ++r)
                cS[(lq * 4 + r) * 1024 + col] = acc[u][r];
        }
        __syncthreads();   // wS reuse + cS visibility
    }

    // epilogue: wave wv owns rows wv*4 .. wv*4+3
    for (int rr = 0; rr < 4; ++rr) {
        int row  = wv * 4 + rr;
        int grow = r0 + row;
        int jm   = grow & 63;
        const float* Bp = B3  + jm * 512;
        const float* Ap = A3T + jm * 512;
        float sum = 0.f, ssq = 0.f, S1 = 0.f, SU = 0.f, SBB = 0.f;
#pragma unroll
        for (int k = 0; k < 8; ++k) {
            int col = ln + k * 64;
            float y  = cS[row * 1024 + col];
            float Bv = Bp[col];
            float gv = g3[col];
            float bv = b3[col];
            float u = gv * Bv;
            sum += y;
            ssq = fmaf(y, y, ssq);
            S1  = fmaf(y, u, S1);
            SU  += u;
            SBB = fmaf(bv, Bv, SBB);
        }
#pragma unroll
        for (int m = 1; m < 64; m <<= 1) {
            sum += __shfl_xor(sum, m, 64);
            ssq += __shfl_xor(ssq, m, 64);
            S1  += __shfl_xor(S1, m, 64);
            SU  += __shfl_xor(SU, m, 64);
            SBB += __shfl_xor(SBB, m, 64);
        }
        float mean = sum * (1.0f / 512.0f);
        float var  = ssq * (1.0f / 512.0f) - mean * mean;
        float rstd = rsqrtf(var + 1e-5f);
        float p = rstd * (S1 - mean * SU) + SBB;
#pragma unroll
        for (int k = 0; k < 8; ++k) {
            int col = ln + k * 64;
            float res = cS[row * 1024 + 512 + col];
            outf[(size_t)grow * 512 + col] = fmaf(p, Ap[col], res);
        }
    }
}

// ---------------------------------------------------------------------------
extern "C" void kernel_launch(void* const* d_in, const int* in_sizes, int n_in,
                              void* d_out, int out_size, void* d_ws, size_t ws_size,
                              hipStream_t stream) {
    (void)in_sizes; (void)n_in; (void)out_size; (void)ws_size;
    const float* x  = (const float*)d_in[0];
    const float* W1 = (const float*)d_in[1];
    const float* g1 = (const float*)d_in[2];
    const float* b1 = (const float*)d_in[3];
    const float* A1 = (const float*)d_in[4];
    const float* B1 = (const float*)d_in[5];
    const float* M2 = (const float*)d_in[6];
    const float* g2 = (const float*)d_in[7];
    const float* b2 = (const float*)d_in[8];
    const float* P2 = (const float*)d_in[9];
    const float* R2 = (const float*)d_in[10];
    const float* W3 = (const float*)d_in[11];
    const float* g3 = (const float*)d_in[12];
    const float* b3 = (const float*)d_in[13];
    const float* A3 = (const float*)d_in[14];
    const float* B3 = (const float*)d_in[15];
    const float* R3 = (const float*)d_in[16];

    float* ws = (float*)d_ws;
    float* C2   = ws;                  // 2 x 524,288 fp32 partials (y|res, ld 128)
    float* t    = ws + 4194304;        // 262,144
    float* rsum = ws + 4456448;        // 262,144 (must follow t: overrun pad)
    float* G2y  = ws + 4718592;        // 4,096
    float* G2r  = ws + 4722688;        // 4,096
    float* A3T  = ws + 4751360;        // 32,768
    unsigned short* us = (unsigned short*)(ws + 4784128);
    unsigned short* xh   = us;                  // 2,097,152
    unsigned short* xl   = us + 2097152;        // 2,097,152
    unsigned short* W1h  = us + 6291456;        // 262,144 (rows 0..511 of Wbig)
    unsigned short* Wc2h = us + 6553600;        // 65,536  (rows 512..639 of Wbig)
    unsigned short* Wc3h = us + 6619136;        // 65,536 (1024 x 64)
    unsigned short* h2h  = us + 6684672;        // 262,144
    unsigned short* h2l  = us + 6946816;        // 262,144
    unsigned short* C1b  = us + 7208960;        // 2 x 2,097,152 (bf16 partials)

    dim3 blk(256);

    // 0) convert x (hi+lo) + weights (hi) + A3 transpose + G2y/G2r
    convk<<<1472, blk, 0, stream>>>(x, W1, M2, R2, W3, R3, A1, A3,
                                    xh, xl, W1h, Wc2h, Wc3h, A3T, G2y, G2r);

    // 1) merged GEMM: [C1 | C2y | C2r] = x @ [W1; M2; R2]^T
    //    64x128 tiles (wide-N halves A re-reads), split-K=2, 640 blocks
    gemmw<<<dim3(5, 64, 2), blk, 0, stream>>>(xh, xl, W1h, C2, C1b, 512, 256);

    // 2) p from C1 row-reduces; t = LN64(C2y + p*G2y); rsum = C2r + p*G2r
    ptk<<<1024, blk, 0, stream>>>(C1b, C2, B1, g1, b1, g2, b2, G2y, G2r, t, rsum);

    // 3) TS Chebyshev recurrence -> h2 (hi/lo)
    tsk2<<<512, blk, 0, stream>>>(t, rsum, P2, h2h, h2l);

    // 4) fused layer-3: GEMM(K=64, hi+lo) + LN + rank-1 + residual -> out
    g3ln<<<256, blk, 0, stream>>>(h2h, h2l, Wc3h, g3, b3, B3, A3T, (float*)d_out);
}